// Round 9
// baseline (550.421 us; speedup 1.0000x reference)
//
#include <hip/hip_runtime.h>
#include <hip/hip_bf16.h>

#define B_    8
#define O_    4
#define L_    1024
#define E_    1024
#define BETA_ 512
#define NSEG_ 12
#define BO_   32
#define NCH_  64   // k1: 16-row chunks, 64 per bo

// ---- workspace layout (float offsets). NO zero-init needed anywhere. (~180 MB < ws)
enum : size_t {
  WS_SPART = 0,                                        // [32][64][12][1024] sparse chunk partials
  WS_X     = WS_SPART + (size_t)BO_ * NCH_ * 12 * E_,  // [32][13][1024]
  WS_P1P   = WS_X     + (size_t)BO_ * 13 * E_,         // [16][32][13][1024]
  WS_TE    = WS_P1P   + (size_t)16 * BO_ * 13 * E_,    // [32][13][1024]  1+relu(P1+bp)
  WS_H1P   = WS_TE    + (size_t)BO_ * 13 * E_,         // [16][32][10][512]
  WS_T1P   = WS_H1P   + (size_t)16 * BO_ * 10 * BETA_, // [16][32][10][512]
  WS_T1B   = WS_T1P   + (size_t)16 * BO_ * 10 * BETA_, // [32][10][512]
  WS_IAB   = WS_T1B   + (size_t)BO_ * 10 * BETA_,      // [32][1024]
  WS_H2P   = WS_IAB   + (size_t)BO_ * 2 * BETA_,       // [16][32][512]
  WS_T2P   = WS_H2P   + (size_t)16 * BO_ * BETA_,      // [16][32][512]
  WS_RN    = WS_T2P   + (size_t)16 * BO_ * BETA_,      // [32][10][1024]
  WS_H3P   = WS_RN    + (size_t)BO_ * 10 * E_,         // [16][32][10][512]
  WS_T3P   = WS_H3P   + (size_t)16 * BO_ * 10 * BETA_, // [16][32][10][512]
  WS_HFP   = WS_T3P   + (size_t)16 * BO_ * 10 * BETA_, // [32][32][512]
  WS_END   = WS_HFP   + (size_t)32 * BO_ * BETA_,
};

__device__ __forceinline__ float relu_(float v) { return v > 0.f ? v : 0.f; }

// ---------------- K1: overlap-aware per-chunk segment partial sums (16-row chunks) ----
__global__ void k1_segsum(const float* __restrict__ hidden, const int* __restrict__ idx,
                          float* __restrict__ Spart) {
    const int chunk = blockIdx.x;  // 0..63, 16 rows each
    const int bo = blockIdx.y;
    const int b = bo >> 2;
    int cuts[13];
    cuts[0] = 1;
#pragma unroll
    for (int i = 0; i < 12; ++i) cuts[i + 1] = idx[b * NSEG_ + i];
    const int l0 = chunk * 16;
    const int l1 = l0 + 16;
    int lo = l0 < 1 ? 1 : l0;
    const int hi = l1 < cuts[12] ? l1 : cuts[12];
    if (lo >= hi) return;
    const int e4 = threadIdx.x << 2;
    const float* base = hidden + (size_t)bo * (L_ * E_) + e4;
    float* sp = Spart + (size_t)(bo * NCH_ + chunk) * 12 * E_ + e4;
    int j = 0;
    while (j < 11 && cuts[j + 1] <= lo) ++j;
    int l = lo;
    while (l < hi) {
        const int e2 = (j < 11 && cuts[j + 1] < hi) ? cuts[j + 1] : hi;
        float sx = 0.f, sy = 0.f, sz = 0.f, sw = 0.f;
        float tx = 0.f, ty = 0.f, tz = 0.f, tw = 0.f;
        for (; l + 1 < e2; l += 2) {  // 2 loads in flight
            const float4 v0 = *reinterpret_cast<const float4*>(base + (size_t)l * E_);
            const float4 v1 = *reinterpret_cast<const float4*>(base + (size_t)(l + 1) * E_);
            sx += v0.x; sy += v0.y; sz += v0.z; sw += v0.w;
            tx += v1.x; ty += v1.y; tz += v1.z; tw += v1.w;
        }
        if (l < e2) {
            const float4 v = *reinterpret_cast<const float4*>(base + (size_t)l * E_);
            sx += v.x; sy += v.y; sz += v.z; sw += v.w;
            ++l;
        }
        float4 s; s.x = sx + tx; s.y = sy + ty; s.z = sz + tz; s.w = sw + tw;
        *reinterpret_cast<float4*>(sp + (size_t)j * E_) = s;
        ++j;
    }
}

// ---------------- K2: reduce intersecting chunk partials -> means ---------------------
__global__ __launch_bounds__(256) void k2_means(
    const float* __restrict__ Spart, const int* __restrict__ idx,
    float* __restrict__ X) {
    const int bo = blockIdx.y;
    const int col = blockIdx.x * 256 + threadIdx.x;
    const int b = bo >> 2;
    int cuts[13];
    cuts[0] = 1;
#pragma unroll
    for (int i = 0; i < 12; ++i) cuts[i + 1] = idx[b * NSEG_ + i];
    const float* sp = Spart + (size_t)bo * NCH_ * 12 * E_ + col;
    float allc = 0.f;
#pragma unroll
    for (int m = 0; m < 12; ++m) {
        const int c0 = cuts[m] >> 4;
        const int c1 = (cuts[m + 1] - 1) >> 4;
        float s = 0.f;
        for (int ch = c0; ch <= c1; ++ch) s += sp[((size_t)ch * 12 + m) * E_];
        X[((size_t)bo * 13 + m) * E_ + col] = s / (float)(cuts[m + 1] - cuts[m]);
        if (m < 10) allc += s;
    }
    X[((size_t)bo * 13 + 12) * E_ + col] = allc / (float)(cuts[10] - 1);
}

// ---- NC=4 split-K GEMM: block covers ALL N cols (NC=N/NT cols/thread), LDS-staged x --
// OUTP[((kidx*32+bo)*M + m)*N + c] = sum_{k in [k0,k0+KC)} xval(bo,m,k) * W[k*N+c]
// XF 0 identity | 1 TE=1+relu(ΣXp+b), side TE | 2 relu(ΣXp+b) | 4 pool1->IAB (side IAB,T1B)
// XF 5 pool2->RN (side RN, reads SIDE2=IAB) | 6 pool3+cat
template<int M, int ML, int K, int N, int KC, int BOG, int NT, int XF, int NPART>
__global__ __launch_bounds__(NT) void gemm_nc(
    const float* __restrict__ Xb, const float* __restrict__ xbias,
    const float* __restrict__ W, float* __restrict__ OUTP,
    const float* __restrict__ A0, const float* __restrict__ A1,
    const float* __restrict__ A2, const float* __restrict__ A3,
    float* __restrict__ SIDE, float* __restrict__ SIDE2) {
    constexpr int NC = N / NT;
    const int kidx = blockIdx.x;
    const int k0 = kidx * KC;
    const int bo0 = blockIdx.y * BOG;
    const int tid = threadIdx.x;
    __shared__ __align__(16) float xs[BOG * ML * KC];

    for (int i = tid; i < BOG * ML * KC; i += NT) {
        const int kk = i % KC;
        const int rm = i / KC;
        const int m = rm % ML;
        const int bb = rm / ML;
        const int bo = bo0 + bb;
        const int k = k0 + kk;
        float v;
        if constexpr (XF == 0) {
            v = Xb[((size_t)bo * ML + m) * K + k];
        } else if constexpr (XF == 1) {
            float s = xbias[k];
#pragma unroll
            for (int p = 0; p < NPART; ++p)
                s += Xb[(((size_t)p * BO_ + bo) * ML + m) * K + k];
            v = 1.f + relu_(s);
            SIDE[((size_t)bo * ML + m) * K + k] = v;  // TE
        } else if constexpr (XF == 2) {
            float s = xbias[k];
#pragma unroll
            for (int p = 0; p < NPART; ++p)
                s += Xb[(((size_t)p * BO_ + bo) * ML + m) * K + k];
            v = relu_(s);
        } else if constexpr (XF == 4) {
            const int col = k & 511, half = k >> 9;
            const float bac = A2[col];
            float t[10], mx = -1e30f;
#pragma unroll
            for (int j = 0; j < 10; ++j) {
                float s = bac;
#pragma unroll
                for (int p = 0; p < NPART; ++p)
                    s += A0[(((size_t)p * BO_ + bo) * 10 + j) * BETA_ + col];
                t[j] = s;
                mx = fmaxf(mx, s);
            }
            if (half == 0) {
#pragma unroll
                for (int j = 0; j < 10; ++j)
                    SIDE2[((size_t)bo * 10 + j) * BETA_ + col] = t[j];  // T1B
            }
            float sw = 0.f, acc = 0.f;
#pragma unroll
            for (int j = 0; j < 10; ++j) {
                const float pj = expf(t[j] - mx);
                sw += pj;
                acc = fmaf(pj, A1[((size_t)bo * 13 + j) * E_ + half * BETA_ + col], acc);
            }
            v = acc / sw;
            SIDE[(size_t)bo * 1024 + k] = v;  // IAB
        } else if constexpr (XF == 5) {
            const int col = k & 511, half = k >> 9;
            const float tj = A0[((size_t)bo * 10 + m) * BETA_ + col];  // T1B
            float tI = A2[col];
#pragma unroll
            for (int p = 0; p < NPART; ++p)
                tI += A1[((size_t)p * BO_ + bo) * BETA_ + col];
            const float mx = fmaxf(tj, tI);
            const float e0 = expf(tj - mx);
            const float e1 = expf(tI - mx);
            const float ea = A3[((size_t)bo * 13 + m) * E_ + half * BETA_ + col];  // TE
            const float iv = SIDE2[(size_t)bo * 1024 + k];                         // IAB
            v = (e0 + e1) / (e0 * ea + e1 * iv);
            SIDE[((size_t)bo * 10 + m) * E_ + k] = v;  // RN
        } else {  // XF == 6
            if (k < 1024) {
                const int col = k & 511;
                const float bac = A2[col];
                float t[10], mx = -1e30f;
#pragma unroll
                for (int j = 0; j < 10; ++j) {
                    float s = bac;
#pragma unroll
                    for (int p = 0; p < NPART; ++p)
                        s += A0[(((size_t)p * BO_ + bo) * 10 + j) * BETA_ + col];
                    t[j] = s;
                    mx = fmaxf(mx, s);
                }
                float sw = 0.f, acc = 0.f;
#pragma unroll
                for (int j = 0; j < 10; ++j) {
                    const float pj = expf(t[j] - mx);
                    sw += pj;
                    acc = fmaf(pj, A1[((size_t)bo * 10 + j) * E_ + k], acc);  // RN
                }
                v = sw / acc;
            } else {
                const int region = k >> 10;
                const int row = (region == 1) ? 12 : (region == 2) ? 11 : 10;
                v = A3[((size_t)bo * 13 + row) * E_ + (k & 1023)];  // TE rows
            }
        }
        xs[i] = v;
    }
    __syncthreads();

    float acc[BOG][M][NC];
#pragma unroll
    for (int b = 0; b < BOG; ++b)
#pragma unroll
        for (int m = 0; m < M; ++m)
#pragma unroll
            for (int q = 0; q < NC; ++q) acc[b][m][q] = 0.f;
    const float* __restrict__ wp = W + (size_t)k0 * N + tid;
    for (int k4 = 0; k4 < KC / 4; ++k4) {
        float w[4][NC];
#pragma unroll
        for (int kk = 0; kk < 4; ++kk)
#pragma unroll
            for (int q = 0; q < NC; ++q)
                w[kk][q] = wp[(size_t)(4 * k4 + kk) * N + q * NT];
#pragma unroll
        for (int b = 0; b < BOG; ++b) {
#pragma unroll
            for (int m = 0; m < M; ++m) {
                const float4 xv = *reinterpret_cast<const float4*>(&xs[(b * ML + m) * KC + 4 * k4]);
#pragma unroll
                for (int q = 0; q < NC; ++q) {
                    float a = acc[b][m][q];
                    a = fmaf(xv.x, w[0][q], a);
                    a = fmaf(xv.y, w[1][q], a);
                    a = fmaf(xv.z, w[2][q], a);
                    a = fmaf(xv.w, w[3][q], a);
                    acc[b][m][q] = a;
                }
            }
        }
    }
#pragma unroll
    for (int b = 0; b < BOG; ++b) {
        float* op = OUTP + (((size_t)kidx * BO_ + bo0 + b) * M) * N + tid;
#pragma unroll
        for (int m = 0; m < M; ++m)
#pragma unroll
            for (int q = 0; q < NC; ++q) op[(size_t)m * N + q * NT] = acc[b][m][q];
    }
}

// ---------------- final: out[bo] = relu(sum_p HFpart + bl0) . Wl + bl -----------------
__global__ void __launch_bounds__(512) k_final(
    const float* __restrict__ HFP, const float* __restrict__ bl0,
    const float* __restrict__ Wl, const float* __restrict__ bl,
    float* __restrict__ out) {
    const int bo = blockIdx.x;
    const int c = threadIdx.x;
    float s = bl0[c];
#pragma unroll
    for (int p = 0; p < 32; ++p) s += HFP[((size_t)p * BO_ + bo) * BETA_ + c];
    float partial = relu_(s) * Wl[c];
#pragma unroll
    for (int off = 32; off > 0; off >>= 1) partial += __shfl_down(partial, off, 64);
    __shared__ float red[8];
    if ((c & 63) == 0) red[c >> 6] = partial;
    __syncthreads();
    if (c == 0) out[bo] = red[0] + red[1] + red[2] + red[3] + red[4] + red[5] + red[6] + red[7] + bl[0];
}

extern "C" void kernel_launch(void* const* d_in, const int* in_sizes, int n_in,
                              void* d_out, int out_size, void* d_ws, size_t ws_size,
                              hipStream_t stream) {
    const float* hidden = (const float*)d_in[0];
    const int* idx = (const int*)d_in[1];
    const float* Wp  = (const float*)d_in[2];
    const float* bp  = (const float*)d_in[3];
    const float* Wa0 = (const float*)d_in[4];
    const float* ba0 = (const float*)d_in[5];
    const float* Wa  = (const float*)d_in[6];
    const float* ba  = (const float*)d_in[7];
    const float* Wl0 = (const float*)d_in[8];
    const float* bl0 = (const float*)d_in[9];
    const float* Wl  = (const float*)d_in[10];
    const float* bl  = (const float*)d_in[11];
    float* ws = (float*)d_ws;
    float* SPART = ws + WS_SPART;
    float* X     = ws + WS_X;
    float* P1P   = ws + WS_P1P;
    float* TE    = ws + WS_TE;
    float* H1P   = ws + WS_H1P;
    float* T1P   = ws + WS_T1P;
    float* T1B   = ws + WS_T1B;
    float* IAB   = ws + WS_IAB;
    float* H2P   = ws + WS_H2P;
    float* T2P   = ws + WS_T2P;
    float* RN    = ws + WS_RN;
    float* H3P   = ws + WS_H3P;
    float* T3P   = ws + WS_T3P;
    float* HFP   = ws + WS_HFP;
    const float* NUL = nullptr;

    k1_segsum<<<dim3(NCH_, BO_), 256, 0, stream>>>(hidden, idx, SPART);
    k2_means<<<dim3(4, BO_), 256, 0, stream>>>(SPART, idx, X);
    // G1: P1P[16] = X @ Wp  (M=13, K=1024, N=1024), 256 blocks x 256 thr, NC=4
    gemm_nc<13, 13, 1024, 1024, 64, 2, 256, 0, 1>
        <<<dim3(16, 16), 256, 0, stream>>>(X, NUL, Wp, P1P, NUL, NUL, NUL, NUL, nullptr, nullptr);
    // G2: H1P[16] = TE(rows<10) @ Wa0 ; loader reduces P1P + writes TE
    gemm_nc<10, 13, 1024, 512, 64, 2, 128, 1, 16>
        <<<dim3(16, 16), 128, 0, stream>>>(P1P, bp, Wa0, H1P, NUL, NUL, NUL, NUL, TE, nullptr);
    // G3: T1P[16] = relu(ΣH1P+ba0) @ Wa
    gemm_nc<10, 10, 512, 512, 32, 2, 128, 2, 16>
        <<<dim3(16, 16), 128, 0, stream>>>(H1P, ba0, Wa, T1P, NUL, NUL, NUL, NUL, nullptr, nullptr);
    // G4: H2P[16] = IAB @ Wa0 ; pool-1 softmax loader (side IAB, T1B)
    gemm_nc<1, 1, 1024, 512, 64, 8, 128, 4, 16>
        <<<dim3(16, 4), 128, 0, stream>>>(NUL, NUL, Wa0, H2P, T1P, TE, ba, NUL, IAB, T1B);
    // G5: T2P[16] = relu(ΣH2P+ba0) @ Wa
    gemm_nc<1, 1, 512, 512, 32, 8, 128, 2, 16>
        <<<dim3(16, 4), 128, 0, stream>>>(H2P, ba0, Wa, T2P, NUL, NUL, NUL, NUL, nullptr, nullptr);
    // G6: H3P[16] = RN @ Wa0 ; pool-2 2-way softmax loader (side RN)
    gemm_nc<10, 10, 1024, 512, 64, 2, 128, 5, 16>
        <<<dim3(16, 16), 128, 0, stream>>>(NUL, NUL, Wa0, H3P, T1B, T2P, ba, TE, RN, IAB);
    // G7: T3P[16] = relu(ΣH3P+ba0) @ Wa
    gemm_nc<10, 10, 512, 512, 32, 2, 128, 2, 16>
        <<<dim3(16, 16), 128, 0, stream>>>(H3P, ba0, Wa, T3P, NUL, NUL, NUL, NUL, nullptr, nullptr);
    // G8: HFP[32] = CAT @ Wl0 ; pool-3 softmax + cat loader (K=4096)
    gemm_nc<1, 1, 4096, 512, 128, 8, 128, 6, 16>
        <<<dim3(32, 4), 128, 0, stream>>>(NUL, NUL, Wl0, HFP, T3P, RN, ba, TE, nullptr, nullptr);
    k_final<<<BO_, 512, 0, stream>>>(HFP, bl0, Wl, bl, (float*)d_out);
}

// Round 10
// 206.622 us; speedup vs baseline: 2.6639x; 2.6639x over previous
//
#include <hip/hip_runtime.h>
#include <hip/hip_bf16.h>

#define B_    8
#define O_    4
#define L_    1024
#define E_    1024
#define BETA_ 512
#define NSEG_ 12
#define BO_   32
#define NCH_  16   // k1 row-chunks per bo (64 rows each)

// ---- workspace layout (float offsets). NO zero-init required anywhere.
enum : size_t {
  WS_SPART = 0,                                       // [32][16][12][1024] k1 chunk partials
  WS_X     = WS_SPART + (size_t)BO_ * NCH_ * 12 * E_, // [32][13][1024] segment means
  WS_P1P   = WS_X     + (size_t)BO_ * 13 * E_,        // [16][32][13][1024] X@Wp partials
  WS_H1P   = WS_P1P   + (size_t)16 * BO_ * 13 * E_,   // [16][32][10][512]
  WS_T1P   = WS_H1P   + (size_t)16 * BO_ * 10 * BETA_,// [4][32][10][512]
  WS_H2P   = WS_T1P   + (size_t)4  * BO_ * 10 * BETA_,// [16][32][512]
  WS_T2P   = WS_H2P   + (size_t)16 * BO_ * BETA_,     // [16][32][512]
  WS_H3P   = WS_T2P   + (size_t)16 * BO_ * BETA_,     // [16][32][10][512]
  WS_T3P   = WS_H3P   + (size_t)16 * BO_ * 10 * BETA_,// [4][32][10][512]
  WS_HFP   = WS_T3P   + (size_t)4  * BO_ * 10 * BETA_,// [64][32][512]
  WS_TE    = WS_HFP   + (size_t)64 * BO_ * BETA_,     // [32][13][1024] 1+relu(P1+bp)
  WS_T1B   = WS_TE    + (size_t)BO_ * 13 * E_,        // [32][10][512] T1+ba
  WS_IAB   = WS_T1B   + (size_t)BO_ * 10 * BETA_,     // [32][1024] ia|ib
  WS_RN    = WS_IAB   + (size_t)BO_ * 2 * BETA_,      // [32][10][1024] 1/na|1/nb
  WS_END   = WS_RN    + (size_t)BO_ * 10 * E_,
};

__device__ __forceinline__ float relu_(float v) { return v > 0.f ? v : 0.f; }

// ---------------- K1: per-chunk segment partial sums (plain stores, no atomics) -------
__global__ void k1_segsum(const float* __restrict__ hidden, const int* __restrict__ idx,
                          float* __restrict__ Spart) {
    const int chunk = blockIdx.x;  // 0..15, 64 rows each
    const int bo = blockIdx.y;
    const int b = bo >> 2;
    int cuts[13];
    cuts[0] = 1;
#pragma unroll
    for (int i = 0; i < 12; ++i) cuts[i + 1] = idx[b * NSEG_ + i];
    const int e4 = threadIdx.x << 2;
    float* sp = Spart + ((size_t)(bo * NCH_ + chunk) * 12) * E_ + e4;
    const float4 z = make_float4(0.f, 0.f, 0.f, 0.f);
#pragma unroll
    for (int m = 0; m < 12; ++m) *reinterpret_cast<float4*>(sp + (size_t)m * E_) = z;
    const int l0 = chunk * 64;
    const int l1 = l0 + 64;
    int lo = l0 < 1 ? 1 : l0;
    const int hi = l1 < cuts[12] ? l1 : cuts[12];
    if (lo >= hi) return;
    const float* base = hidden + (size_t)bo * (L_ * E_) + e4;
    int j = 0;
    while (j < 11 && cuts[j + 1] <= lo) ++j;
    int l = lo;
    while (l < hi) {
        const int e2 = (j < 11 && cuts[j + 1] < hi) ? cuts[j + 1] : hi;
        float sx = 0.f, sy = 0.f, sz = 0.f, sw = 0.f;
        for (; l < e2; ++l) {
            const float4 v = *reinterpret_cast<const float4*>(base + (size_t)l * E_);
            sx += v.x; sy += v.y; sz += v.z; sw += v.w;
        }
        float4 s; s.x = sx; s.y = sy; s.z = sz; s.w = sw;
        *reinterpret_cast<float4*>(sp + (size_t)j * E_) = s;  // block-owned slice
        ++j;
    }
}

// ---------------- K2: reduce chunk partials -> segment means X[32][13][1024] ----------
__global__ __launch_bounds__(256) void k2_means(
    const float* __restrict__ Spart, const int* __restrict__ idx,
    float* __restrict__ X) {
    const int bo = blockIdx.y;
    const int col = blockIdx.x * 256 + threadIdx.x;
    const int b = bo >> 2;
    int cuts[13];
    cuts[0] = 1;
#pragma unroll
    for (int i = 0; i < 12; ++i) cuts[i + 1] = idx[b * NSEG_ + i];
    const float* sp = Spart + (size_t)bo * NCH_ * 12 * E_ + col;
    float allc = 0.f;
#pragma unroll
    for (int m = 0; m < 12; ++m) {
        float s = 0.f;
#pragma unroll
        for (int ch = 0; ch < NCH_; ++ch) s += sp[((size_t)ch * 12 + m) * E_];
        X[((size_t)bo * 13 + m) * E_ + col] = s / (float)(cuts[m + 1] - cuts[m]);
        if (m < 10) allc += s;
    }
    X[((size_t)bo * 13 + 12) * E_ + col] = allc / (float)(cuts[10] - 1);
}

// ---------------- split-K GEMM, partial-slice output (no atomics) ---------------------
// OUTpart[((kidx*32+bo)*M + m)*N + c] = sum_{k in slice} xval(bo,m,k) * W[k*N+c]
// XF 0: identity | 1: 1+relu(sum_p+xb), side TE | 2: relu(sum_p+xb)
// XF 4: pool1 softmax -> IAB (sides T1B, IAB) | 5: pool2 -> RN | 6: pool3 + cat
template<int M, int ML, int K, int N, int KC, int BOG, int XF, int NPART>
__global__ __launch_bounds__(256) void gemm_sk(
    const float* __restrict__ Xb, const float* __restrict__ xbias,
    const float* __restrict__ W, float* __restrict__ OUT,
    const float* __restrict__ A0, const float* __restrict__ A1,
    const float* __restrict__ A2, const float* __restrict__ A3,
    float* __restrict__ SIDE, float* __restrict__ SIDE2) {
    const int kidx = blockIdx.x;
    const int k0 = kidx * KC;
    const int bo0 = blockIdx.y * BOG;
    const int c = blockIdx.z * 256 + threadIdx.x;
    const int tid = threadIdx.x;
    __shared__ __align__(16) float xs[BOG * ML * KC];

    for (int i = tid; i < BOG * ML * KC; i += 256) {
        const int kk = i % KC;
        const int rm = i / KC;
        const int m = rm % ML;
        const int bb = rm / ML;
        const int bo = bo0 + bb;
        const int k = k0 + kk;
        float v;
        if constexpr (XF == 0) {
            v = Xb[((size_t)bo * ML + m) * K + k];
        } else if constexpr (XF == 1) {
            float s = xbias[k];
#pragma unroll
            for (int p = 0; p < NPART; ++p)
                s += Xb[(((size_t)p * BO_ + bo) * ML + m) * K + k];
            v = 1.f + relu_(s);
            SIDE[((size_t)bo * ML + m) * K + k] = v;  // TE
        } else if constexpr (XF == 2) {
            float s = xbias[k];
#pragma unroll
            for (int p = 0; p < NPART; ++p)
                s += Xb[(((size_t)p * BO_ + bo) * ML + m) * K + k];
            v = relu_(s);
        } else if constexpr (XF == 4) {
            const int col = k & 511, half = k >> 9;
            const float bac = A2[col];
            float t[10], mx = -1e30f;
#pragma unroll
            for (int j = 0; j < 10; ++j) {
                float s = bac;
#pragma unroll
                for (int p = 0; p < NPART; ++p)
                    s += A0[(((size_t)p * BO_ + bo) * 10 + j) * BETA_ + col];
                t[j] = s;
                mx = fmaxf(mx, s);
            }
            if (half == 0) {
#pragma unroll
                for (int j = 0; j < 10; ++j)
                    SIDE2[((size_t)bo * 10 + j) * BETA_ + col] = t[j];  // T1B
            }
            float sw = 0.f, acc = 0.f;
#pragma unroll
            for (int j = 0; j < 10; ++j) {
                const float pj = expf(t[j] - mx);
                sw += pj;
                acc = fmaf(pj, A1[((size_t)bo * 13 + j) * E_ + half * BETA_ + col], acc);
            }
            v = acc / sw;
            SIDE[(size_t)bo * 1024 + k] = v;  // IAB
        } else if constexpr (XF == 5) {
            const int col = k & 511, half = k >> 9;
            const float tj = A0[((size_t)bo * 10 + m) * BETA_ + col];  // T1B (has +ba)
            float tI = A2[col];
#pragma unroll
            for (int p = 0; p < NPART; ++p)
                tI += A1[((size_t)p * BO_ + bo) * BETA_ + col];
            const float mx = fmaxf(tj, tI);
            const float e0 = expf(tj - mx);
            const float e1 = expf(tI - mx);
            const float ea = A3[((size_t)bo * 13 + m) * E_ + half * BETA_ + col];  // TE
            const float iv = SIDE2[(size_t)bo * 1024 + k];                         // IAB
            v = (e0 + e1) / (e0 * ea + e1 * iv);
            SIDE[((size_t)bo * 10 + m) * E_ + k] = v;  // RN
        } else {  // XF == 6
            if (k < 1024) {
                const int col = k & 511;
                const float bac = A2[col];
                float t[10], mx = -1e30f;
#pragma unroll
                for (int j = 0; j < 10; ++j) {
                    float s = bac;
#pragma unroll
                    for (int p = 0; p < NPART; ++p)
                        s += A0[(((size_t)p * BO_ + bo) * 10 + j) * BETA_ + col];
                    t[j] = s;
                    mx = fmaxf(mx, s);
                }
                float sw = 0.f, acc = 0.f;
#pragma unroll
                for (int j = 0; j < 10; ++j) {
                    const float pj = expf(t[j] - mx);
                    sw += pj;
                    acc = fmaf(pj, A1[((size_t)bo * 10 + j) * E_ + k], acc);  // RN
                }
                v = sw / acc;
            } else {
                const int region = k >> 10;
                const int row = (region == 1) ? 12 : (region == 2) ? 11 : 10;
                v = A3[((size_t)bo * 13 + row) * E_ + (k & 1023)];  // TE rows
            }
        }
        xs[i] = v;
    }
    __syncthreads();

    float acc[BOG][M];
#pragma unroll
    for (int b = 0; b < BOG; ++b)
#pragma unroll
        for (int m = 0; m < M; ++m) acc[b][m] = 0.f;
    const float* __restrict__ wp = W + (size_t)k0 * N + c;
    for (int k4 = 0; k4 < KC / 4; ++k4) {
        const float w0 = wp[(size_t)(4 * k4 + 0) * N];
        const float w1 = wp[(size_t)(4 * k4 + 1) * N];
        const float w2 = wp[(size_t)(4 * k4 + 2) * N];
        const float w3 = wp[(size_t)(4 * k4 + 3) * N];
#pragma unroll
        for (int b = 0; b < BOG; ++b) {
#pragma unroll
            for (int m = 0; m < M; ++m) {
                const float4 xv = *reinterpret_cast<const float4*>(&xs[(b * ML + m) * KC + 4 * k4]);
                float a = acc[b][m];
                a = fmaf(xv.x, w0, a);
                a = fmaf(xv.y, w1, a);
                a = fmaf(xv.z, w2, a);
                a = fmaf(xv.w, w3, a);
                acc[b][m] = a;
            }
        }
    }
#pragma unroll
    for (int b = 0; b < BOG; ++b) {
        float* op = OUT + (((size_t)kidx * BO_ + bo0 + b) * M) * N + c;
#pragma unroll
        for (int m = 0; m < M; ++m) op[(size_t)m * N] = acc[b][m];  // plain store
    }
}

// ---------------- final: out[bo] = relu(sum_p HFpart + bl0) . Wl + bl -----------------
__global__ void __launch_bounds__(512) k_final(
    const float* __restrict__ HFP, const float* __restrict__ bl0,
    const float* __restrict__ Wl, const float* __restrict__ bl,
    float* __restrict__ out) {
    const int bo = blockIdx.x;
    const int c = threadIdx.x;
    float s = bl0[c];
#pragma unroll
    for (int p = 0; p < 64; ++p) s += HFP[((size_t)p * BO_ + bo) * BETA_ + c];
    float partial = relu_(s) * Wl[c];
#pragma unroll
    for (int off = 32; off > 0; off >>= 1) partial += __shfl_down(partial, off, 64);
    __shared__ float red[8];
    if ((c & 63) == 0) red[c >> 6] = partial;
    __syncthreads();
    if (c == 0) out[bo] = red[0] + red[1] + red[2] + red[3] + red[4] + red[5] + red[6] + red[7] + bl[0];
}

extern "C" void kernel_launch(void* const* d_in, const int* in_sizes, int n_in,
                              void* d_out, int out_size, void* d_ws, size_t ws_size,
                              hipStream_t stream) {
    const float* hidden = (const float*)d_in[0];
    const int* idx = (const int*)d_in[1];
    const float* Wp  = (const float*)d_in[2];
    const float* bp  = (const float*)d_in[3];
    const float* Wa0 = (const float*)d_in[4];
    const float* ba0 = (const float*)d_in[5];
    const float* Wa  = (const float*)d_in[6];
    const float* ba  = (const float*)d_in[7];
    const float* Wl0 = (const float*)d_in[8];
    const float* bl0 = (const float*)d_in[9];
    const float* Wl  = (const float*)d_in[10];
    const float* bl  = (const float*)d_in[11];
    float* ws = (float*)d_ws;
    float* SPART = ws + WS_SPART;
    float* X     = ws + WS_X;
    float* P1P   = ws + WS_P1P;
    float* H1P   = ws + WS_H1P;
    float* T1P   = ws + WS_T1P;
    float* H2P   = ws + WS_H2P;
    float* T2P   = ws + WS_T2P;
    float* H3P   = ws + WS_H3P;
    float* T3P   = ws + WS_T3P;
    float* HFP   = ws + WS_HFP;
    float* TE    = ws + WS_TE;
    float* T1B   = ws + WS_T1B;
    float* IAB   = ws + WS_IAB;
    float* RN    = ws + WS_RN;
    const float* NUL = nullptr;

    k1_segsum<<<dim3(NCH_, BO_), 256, 0, stream>>>(hidden, idx, SPART);
    k2_means<<<dim3(4, BO_), 256, 0, stream>>>(SPART, idx, X);
    // G1: P1P[16] = X @ Wp  (M=13,K=1024,N=1024, ksplit=16) -> 1024 blocks
    gemm_sk<13, 13, 1024, 1024, 64, 2, 0, 1>
        <<<dim3(16, 16, 4), 256, 0, stream>>>(X, NUL, Wp, P1P, NUL, NUL, NUL, NUL, nullptr, nullptr);
    // G2: H1P[16] = TE(rows<10) @ Wa0 ; side TE (sums 16 P1 partials), BOG=4 -> 256 blocks
    gemm_sk<10, 13, 1024, 512, 64, 4, 1, 16>
        <<<dim3(16, 8, 2), 256, 0, stream>>>(P1P, bp, Wa0, H1P, NUL, NUL, NUL, NUL, TE, nullptr);
    // G3: T1P[4] = relu(sum H1P + ba0) @ Wa  (ksplit=4 keeps G4's loader storm small)
    gemm_sk<10, 10, 512, 512, 128, 2, 2, 16>
        <<<dim3(4, 16, 2), 256, 0, stream>>>(H1P, ba0, Wa, T1P, NUL, NUL, NUL, NUL, nullptr, nullptr);
    // G4: H2P[16] = IAB @ Wa0 ; pool-1 softmax loader (NPART=4); sides IAB, T1B -> 128 blocks
    gemm_sk<1, 1, 1024, 512, 64, 8, 4, 4>
        <<<dim3(16, 4, 2), 256, 0, stream>>>(NUL, NUL, Wa0, H2P, T1P, TE, ba, NUL, IAB, T1B);
    // G5: T2P[16] = relu(sum H2P + ba0) @ Wa -> 128 blocks
    gemm_sk<1, 1, 512, 512, 32, 8, 2, 16>
        <<<dim3(16, 4, 2), 256, 0, stream>>>(H2P, ba0, Wa, T2P, NUL, NUL, NUL, NUL, nullptr, nullptr);
    // G6: H3P[16] = RN @ Wa0 ; pool-2 2-way softmax loader; side RN; BOG=4 -> 256 blocks
    gemm_sk<10, 10, 1024, 512, 64, 4, 5, 16>
        <<<dim3(16, 8, 2), 256, 0, stream>>>(NUL, NUL, Wa0, H3P, T1B, T2P, ba, TE, RN, IAB);
    // G7: T3P[4] = relu(sum H3P + ba0) @ Wa  (ksplit=4 for G8's loader)
    gemm_sk<10, 10, 512, 512, 128, 2, 2, 16>
        <<<dim3(4, 16, 2), 256, 0, stream>>>(H3P, ba0, Wa, T3P, NUL, NUL, NUL, NUL, nullptr, nullptr);
    // G8: HFP[64] = CAT @ Wl0 ; pool-3 softmax + cat loader (NPART=4) -> 512 blocks
    gemm_sk<1, 1, 4096, 512, 64, 8, 6, 4>
        <<<dim3(64, 4, 2), 256, 0, stream>>>(NUL, NUL, Wl0, HFP, T3P, RN, ba, TE, nullptr, nullptr);
    k_final<<<BO_, 512, 0, stream>>>(HFP, bl0, Wl, bl, (float*)d_out);
}

// Round 11
// 178.781 us; speedup vs baseline: 3.0787x; 1.1557x over previous
//
#include <hip/hip_runtime.h>
#include <hip/hip_bf16.h>

#define B_    8
#define O_    4
#define L_    1024
#define E_    1024
#define BETA_ 512
#define NSEG_ 12
#define BO_   32
#define NCH_  16   // k1 row-chunks per bo (64 rows each)

// ---- workspace layout (float offsets). NO zero-init required anywhere.
enum : size_t {
  WS_SPART = 0,                                       // [32][16][12][1024] k1 chunk partials
  WS_X     = WS_SPART + (size_t)BO_ * NCH_ * 12 * E_, // [32][13][1024] segment means
  WS_P1P   = WS_X     + (size_t)BO_ * 13 * E_,        // [8][32][13][1024] X@Wp partials
  WS_H1P   = WS_P1P   + (size_t)8  * BO_ * 13 * E_,   // [16][32][10][512]
  WS_T1P   = WS_H1P   + (size_t)16 * BO_ * 10 * BETA_,// [8][32][10][512]
  WS_H2P   = WS_T1P   + (size_t)8  * BO_ * 10 * BETA_,// [8][32][512]
  WS_T2P   = WS_H2P   + (size_t)8  * BO_ * BETA_,     // [8][32][512]
  WS_H3P   = WS_T2P   + (size_t)8  * BO_ * BETA_,     // [16][32][10][512]
  WS_T3P   = WS_H3P   + (size_t)16 * BO_ * 10 * BETA_,// [8][32][10][512]
  WS_HFP   = WS_T3P   + (size_t)8  * BO_ * 10 * BETA_,// [32][32][512]
  WS_TE    = WS_HFP   + (size_t)32 * BO_ * BETA_,     // [32][13][1024] 1+relu(P1+bp)
  WS_T1B   = WS_TE    + (size_t)BO_ * 13 * E_,        // [32][10][512] T1+ba
  WS_IAB   = WS_T1B   + (size_t)BO_ * 10 * BETA_,     // [32][1024] ia|ib
  WS_RN    = WS_IAB   + (size_t)BO_ * 2 * BETA_,      // [32][10][1024] 1/na|1/nb
  WS_CAT   = WS_RN    + (size_t)BO_ * 10 * E_,        // [32][4096]
  WS_END   = WS_CAT   + (size_t)BO_ * 8 * BETA_,
};

__device__ __forceinline__ float relu_(float v) { return v > 0.f ? v : 0.f; }

// ---------------- K1: per-chunk segment partial sums (plain stores, no atomics) -------
__global__ void k1_segsum(const float* __restrict__ hidden, const int* __restrict__ idx,
                          float* __restrict__ Spart) {
    const int chunk = blockIdx.x;  // 0..15, 64 rows each
    const int bo = blockIdx.y;
    const int b = bo >> 2;
    int cuts[13];
    cuts[0] = 1;
#pragma unroll
    for (int i = 0; i < 12; ++i) cuts[i + 1] = idx[b * NSEG_ + i];
    const int e4 = threadIdx.x << 2;
    float* sp = Spart + ((size_t)(bo * NCH_ + chunk) * 12) * E_ + e4;
    const float4 z = make_float4(0.f, 0.f, 0.f, 0.f);
#pragma unroll
    for (int m = 0; m < 12; ++m) *reinterpret_cast<float4*>(sp + (size_t)m * E_) = z;
    const int l0 = chunk * 64;
    const int l1 = l0 + 64;
    int lo = l0 < 1 ? 1 : l0;
    const int hi = l1 < cuts[12] ? l1 : cuts[12];
    if (lo >= hi) return;
    const float* base = hidden + (size_t)bo * (L_ * E_) + e4;
    int j = 0;
    while (j < 11 && cuts[j + 1] <= lo) ++j;
    int l = lo;
    while (l < hi) {
        const int e2 = (j < 11 && cuts[j + 1] < hi) ? cuts[j + 1] : hi;
        float sx = 0.f, sy = 0.f, sz = 0.f, sw = 0.f;
        for (; l < e2; ++l) {
            const float4 v = *reinterpret_cast<const float4*>(base + (size_t)l * E_);
            sx += v.x; sy += v.y; sz += v.z; sw += v.w;
        }
        float4 s; s.x = sx; s.y = sy; s.z = sz; s.w = sw;
        *reinterpret_cast<float4*>(sp + (size_t)j * E_) = s;  // block-owned slice
        ++j;
    }
}

// ---------------- K2: reduce chunk partials -> segment means X[32][13][1024] ----------
__global__ __launch_bounds__(256) void k2_means(
    const float* __restrict__ Spart, const int* __restrict__ idx,
    float* __restrict__ X) {
    const int bo = blockIdx.y;
    const int col = blockIdx.x * 256 + threadIdx.x;
    const int b = bo >> 2;
    int cuts[13];
    cuts[0] = 1;
#pragma unroll
    for (int i = 0; i < 12; ++i) cuts[i + 1] = idx[b * NSEG_ + i];
    const float* sp = Spart + (size_t)bo * NCH_ * 12 * E_ + col;
    float allc = 0.f;
#pragma unroll
    for (int m = 0; m < 12; ++m) {
        float s = 0.f;
#pragma unroll
        for (int ch = 0; ch < NCH_; ++ch) s += sp[((size_t)ch * 12 + m) * E_];
        X[((size_t)bo * 13 + m) * E_ + col] = s / (float)(cuts[m + 1] - cuts[m]);
        if (m < 10) allc += s;
    }
    X[((size_t)bo * 13 + 12) * E_ + col] = allc / (float)(cuts[10] - 1);
}

// ---------------- split-K GEMM, partial-slice output (no atomics) ---------------------
// XF 0: identity | 1: 1+relu(sum_p+xb), side TE | 2: relu(sum_p+xb) | 5: pool2 -> RN
template<int M, int ML, int K, int N, int KC, int BOG, int XF, int NPART>
__global__ __launch_bounds__(256) void gemm_sk(
    const float* __restrict__ Xb, const float* __restrict__ xbias,
    const float* __restrict__ W, float* __restrict__ OUT,
    const float* __restrict__ A0, const float* __restrict__ A1,
    const float* __restrict__ A2, const float* __restrict__ A3,
    float* __restrict__ SIDE, float* __restrict__ SIDE2) {
    const int kidx = blockIdx.x;
    const int k0 = kidx * KC;
    const int bo0 = blockIdx.y * BOG;
    const int c = blockIdx.z * 256 + threadIdx.x;
    const int tid = threadIdx.x;
    __shared__ __align__(16) float xs[BOG * ML * KC];

    for (int i = tid; i < BOG * ML * KC; i += 256) {
        const int kk = i % KC;
        const int rm = i / KC;
        const int m = rm % ML;
        const int bb = rm / ML;
        const int bo = bo0 + bb;
        const int k = k0 + kk;
        float v;
        if constexpr (XF == 0) {
            v = Xb[((size_t)bo * ML + m) * K + k];
        } else if constexpr (XF == 1) {
            float s = xbias[k];
#pragma unroll
            for (int p = 0; p < NPART; ++p)
                s += Xb[(((size_t)p * BO_ + bo) * ML + m) * K + k];
            v = 1.f + relu_(s);
            SIDE[((size_t)bo * ML + m) * K + k] = v;  // TE
        } else if constexpr (XF == 2) {
            float s = xbias[k];
#pragma unroll
            for (int p = 0; p < NPART; ++p)
                s += Xb[(((size_t)p * BO_ + bo) * ML + m) * K + k];
            v = relu_(s);
        } else {  // XF == 5: pool-2 2-way softmax -> RN
            const int col = k & 511, half = k >> 9;
            const float tj = A0[((size_t)bo * 10 + m) * BETA_ + col];  // T1B (has +ba)
            float tI = A2[col];
#pragma unroll
            for (int p = 0; p < NPART; ++p)
                tI += A1[((size_t)p * BO_ + bo) * BETA_ + col];
            const float mx = fmaxf(tj, tI);
            const float e0 = expf(tj - mx);
            const float e1 = expf(tI - mx);
            const float ea = A3[((size_t)bo * 13 + m) * E_ + half * BETA_ + col];  // TE
            const float iv = SIDE2[(size_t)bo * 1024 + k];                         // IAB
            v = (e0 + e1) / (e0 * ea + e1 * iv);
            SIDE[((size_t)bo * 10 + m) * E_ + k] = v;  // RN
        }
        xs[i] = v;
    }
    __syncthreads();

    float acc[BOG][M];
#pragma unroll
    for (int b = 0; b < BOG; ++b)
#pragma unroll
        for (int m = 0; m < M; ++m) acc[b][m] = 0.f;
    const float* __restrict__ wp = W + (size_t)k0 * N + c;
    for (int k4 = 0; k4 < KC / 4; ++k4) {
        const float w0 = wp[(size_t)(4 * k4 + 0) * N];
        const float w1 = wp[(size_t)(4 * k4 + 1) * N];
        const float w2 = wp[(size_t)(4 * k4 + 2) * N];
        const float w3 = wp[(size_t)(4 * k4 + 3) * N];
#pragma unroll
        for (int b = 0; b < BOG; ++b) {
#pragma unroll
            for (int m = 0; m < M; ++m) {
                const float4 xv = *reinterpret_cast<const float4*>(&xs[(b * ML + m) * KC + 4 * k4]);
                float a = acc[b][m];
                a = fmaf(xv.x, w0, a);
                a = fmaf(xv.y, w1, a);
                a = fmaf(xv.z, w2, a);
                a = fmaf(xv.w, w3, a);
                acc[b][m] = a;
            }
        }
    }
#pragma unroll
    for (int b = 0; b < BOG; ++b) {
        float* op = OUT + (((size_t)kidx * BO_ + bo0 + b) * M) * N + c;
#pragma unroll
        for (int m = 0; m < M; ++m) op[(size_t)m * N] = acc[b][m];  // plain store
    }
}

// ---------------- t_iab: pool-1 logits + softmax -> T1B, IAB (wide, one pass) ---------
__global__ void __launch_bounds__(512) t_iab(
    const float* __restrict__ T1P, const float* __restrict__ ba,
    const float* __restrict__ TE, float* __restrict__ T1B,
    float* __restrict__ IAB) {
    const int bo = blockIdx.x;
    const int c = threadIdx.x;  // 0..511
    const float bac = ba[c];
    float t[10], mx = -1e30f;
#pragma unroll
    for (int j = 0; j < 10; ++j) {
        float s = bac;
#pragma unroll
        for (int p = 0; p < 8; ++p)
            s += T1P[(((size_t)p * BO_ + bo) * 10 + j) * BETA_ + c];
        t[j] = s;
        T1B[((size_t)bo * 10 + j) * BETA_ + c] = s;
        mx = fmaxf(mx, s);
    }
    float p[10], sw = 0.f;
#pragma unroll
    for (int j = 0; j < 10; ++j) { p[j] = expf(t[j] - mx); sw += p[j]; }
    float ia = 0.f, ib = 0.f;
#pragma unroll
    for (int j = 0; j < 10; ++j) {
        ia = fmaf(p[j], TE[((size_t)bo * 13 + j) * E_ + c], ia);
        ib = fmaf(p[j], TE[((size_t)bo * 13 + j) * E_ + BETA_ + c], ib);
    }
    IAB[(size_t)bo * 1024 + c] = ia / sw;
    IAB[(size_t)bo * 1024 + BETA_ + c] = ib / sw;
}

// ---------------- t_cat: pool-3 softmax + full cat build ------------------------------
__global__ __launch_bounds__(256) void t_cat(
    const float* __restrict__ T3P, const float* __restrict__ ba,
    const float* __restrict__ RN, const float* __restrict__ TE,
    float* __restrict__ CAT) {
    const int bo = blockIdx.y;
    const int k = blockIdx.x * 256 + threadIdx.x;  // 0..4095
    float v;
    if (k < 1024) {
        const int col = k & 511;
        const float bac = ba[col];
        float t[10], mx = -1e30f;
#pragma unroll
        for (int j = 0; j < 10; ++j) {
            float s = bac;
#pragma unroll
            for (int p = 0; p < 8; ++p)
                s += T3P[(((size_t)p * BO_ + bo) * 10 + j) * BETA_ + col];
            t[j] = s;
            mx = fmaxf(mx, s);
        }
        float sw = 0.f, acc = 0.f;
#pragma unroll
        for (int j = 0; j < 10; ++j) {
            const float pj = expf(t[j] - mx);
            sw += pj;
            acc = fmaf(pj, RN[((size_t)bo * 10 + j) * E_ + k], acc);
        }
        v = sw / acc;
    } else {
        const int region = k >> 10;  // 1,2,3
        const int row = (region == 1) ? 12 : (region == 2) ? 11 : 10;
        v = TE[((size_t)bo * 13 + row) * E_ + (k & 1023)];
    }
    CAT[(size_t)bo * 4096 + k] = v;
}

// ---------------- final: out[bo] = relu(sum_p HFpart + bl0) . Wl + bl -----------------
__global__ void __launch_bounds__(512) k_final(
    const float* __restrict__ HFP, const float* __restrict__ bl0,
    const float* __restrict__ Wl, const float* __restrict__ bl,
    float* __restrict__ out) {
    const int bo = blockIdx.x;
    const int c = threadIdx.x;
    float s = bl0[c];
#pragma unroll
    for (int p = 0; p < 32; ++p) s += HFP[((size_t)p * BO_ + bo) * BETA_ + c];
    float partial = relu_(s) * Wl[c];
#pragma unroll
    for (int off = 32; off > 0; off >>= 1) partial += __shfl_down(partial, off, 64);
    __shared__ float red[8];
    if ((c & 63) == 0) red[c >> 6] = partial;
    __syncthreads();
    if (c == 0) out[bo] = red[0] + red[1] + red[2] + red[3] + red[4] + red[5] + red[6] + red[7] + bl[0];
}

extern "C" void kernel_launch(void* const* d_in, const int* in_sizes, int n_in,
                              void* d_out, int out_size, void* d_ws, size_t ws_size,
                              hipStream_t stream) {
    const float* hidden = (const float*)d_in[0];
    const int* idx = (const int*)d_in[1];
    const float* Wp  = (const float*)d_in[2];
    const float* bp  = (const float*)d_in[3];
    const float* Wa0 = (const float*)d_in[4];
    const float* ba0 = (const float*)d_in[5];
    const float* Wa  = (const float*)d_in[6];
    const float* ba  = (const float*)d_in[7];
    const float* Wl0 = (const float*)d_in[8];
    const float* bl0 = (const float*)d_in[9];
    const float* Wl  = (const float*)d_in[10];
    const float* bl  = (const float*)d_in[11];
    float* ws = (float*)d_ws;
    float* SPART = ws + WS_SPART;
    float* X     = ws + WS_X;
    float* P1P   = ws + WS_P1P;
    float* H1P   = ws + WS_H1P;
    float* T1P   = ws + WS_T1P;
    float* H2P   = ws + WS_H2P;
    float* T2P   = ws + WS_T2P;
    float* H3P   = ws + WS_H3P;
    float* T3P   = ws + WS_T3P;
    float* HFP   = ws + WS_HFP;
    float* TE    = ws + WS_TE;
    float* T1B   = ws + WS_T1B;
    float* IAB   = ws + WS_IAB;
    float* RN    = ws + WS_RN;
    float* CAT   = ws + WS_CAT;
    const float* NUL = nullptr;

    k1_segsum<<<dim3(NCH_, BO_), 256, 0, stream>>>(hidden, idx, SPART);
    k2_means<<<dim3(4, BO_), 256, 0, stream>>>(SPART, idx, X);
    // G1: P1P[8] = X @ Wp  (M=13,K=1024,N=1024)  BOG=4 -> 256 blocks, Wp traffic x8
    gemm_sk<13, 13, 1024, 1024, 128, 4, 0, 1>
        <<<dim3(8, 8, 4), 256, 0, stream>>>(X, NUL, Wp, P1P, NUL, NUL, NUL, NUL, nullptr, nullptr);
    // G2: H1P[16] = TE(rows<10) @ Wa0 ; side TE (sums 8 P1 partials) -> 512 blocks
    gemm_sk<10, 13, 1024, 512, 64, 2, 1, 8>
        <<<dim3(16, 16, 2), 256, 0, stream>>>(P1P, bp, Wa0, H1P, NUL, NUL, NUL, NUL, TE, nullptr);
    // G3: T1P[8] = relu(sum H1P + ba0) @ Wa -> 256 blocks
    gemm_sk<10, 10, 512, 512, 64, 2, 2, 16>
        <<<dim3(8, 16, 2), 256, 0, stream>>>(H1P, ba0, Wa, T1P, NUL, NUL, NUL, NUL, nullptr, nullptr);
    // pool-1 softmax extracted: T1B + IAB in one wide pass
    t_iab<<<BO_, 512, 0, stream>>>(T1P, ba, TE, T1B, IAB);
    // G4: H2P[8] = IAB @ Wa0  (identity loader) -> 64 blocks
    gemm_sk<1, 1, 1024, 512, 128, 8, 0, 1>
        <<<dim3(8, 4, 2), 256, 0, stream>>>(IAB, NUL, Wa0, H2P, NUL, NUL, NUL, NUL, nullptr, nullptr);
    // G5: T2P[8] = relu(sum H2P + ba0) @ Wa -> 64 blocks
    gemm_sk<1, 1, 512, 512, 64, 8, 2, 8>
        <<<dim3(8, 4, 2), 256, 0, stream>>>(H2P, ba0, Wa, T2P, NUL, NUL, NUL, NUL, nullptr, nullptr);
    // G6: H3P[16] = RN @ Wa0 ; pool-2 2-way softmax loader (cheap); side RN -> 512 blocks
    gemm_sk<10, 10, 1024, 512, 64, 2, 5, 8>
        <<<dim3(16, 16, 2), 256, 0, stream>>>(NUL, NUL, Wa0, H3P, T1B, T2P, ba, TE, RN, IAB);
    // G7: T3P[8] = relu(sum H3P + ba0) @ Wa -> 256 blocks
    gemm_sk<10, 10, 512, 512, 64, 2, 2, 16>
        <<<dim3(8, 16, 2), 256, 0, stream>>>(H3P, ba0, Wa, T3P, NUL, NUL, NUL, NUL, nullptr, nullptr);
    // pool-3 softmax + cat extracted: wide, 512 blocks
    t_cat<<<dim3(16, BO_), 256, 0, stream>>>(T3P, ba, RN, TE, CAT);
    // G8: HFP[32] = CAT @ Wl0  (identity loader, K=4096) -> 256 blocks
    gemm_sk<1, 1, 4096, 512, 128, 8, 0, 1>
        <<<dim3(32, 4, 2), 256, 0, stream>>>(CAT, NUL, Wl0, HFP, NUL, NUL, NUL, NUL, nullptr, nullptr);
    k_final<<<BO_, 512, 0, stream>>>(HFP, bl0, Wl, bl, (float*)d_out);
}

// Round 12
// 158.954 us; speedup vs baseline: 3.4628x; 1.1247x over previous
//
#include <hip/hip_runtime.h>
#include <hip/hip_bf16.h>

#define B_    8
#define O_    4
#define L_    1024
#define E_    1024
#define BETA_ 512
#define NSEG_ 12
#define BO_   32
#define NCH_  16   // k1 row-chunks per bo (64 rows each)

// ---- workspace layout (float offsets). NO zero-init required anywhere.
enum : size_t {
  WS_SPART = 0,                                       // [32][16][12][1024] k1 chunk partials
  WS_X     = WS_SPART + (size_t)BO_ * NCH_ * 12 * E_, // [32][13][1024] segment means
  WS_P1P   = WS_X     + (size_t)BO_ * 13 * E_,        // [8][32][13][1024] X@Wp partials
  WS_H1P   = WS_P1P   + (size_t)8  * BO_ * 13 * E_,   // [16][32][10][512]
  WS_T1P   = WS_H1P   + (size_t)16 * BO_ * 10 * BETA_,// [8][32][10][512]
  WS_H2P   = WS_T1P   + (size_t)8  * BO_ * 10 * BETA_,// [8][32][512]
  WS_T2P   = WS_H2P   + (size_t)8  * BO_ * BETA_,     // [8][32][512]
  WS_H3P   = WS_T2P   + (size_t)8  * BO_ * BETA_,     // [16][32][10][512]
  WS_T3P   = WS_H3P   + (size_t)16 * BO_ * 10 * BETA_,// [8][32][10][512]
  WS_HFP   = WS_T3P   + (size_t)8  * BO_ * 10 * BETA_,// [32][32][512]
  WS_TE    = WS_HFP   + (size_t)32 * BO_ * BETA_,     // [32][13][1024] 1+relu(P1+bp)
  WS_T1B   = WS_TE    + (size_t)BO_ * 13 * E_,        // [32][10][512] T1+ba
  WS_IAB   = WS_T1B   + (size_t)BO_ * 10 * BETA_,     // [32][1024] ia|ib
  WS_RN    = WS_IAB   + (size_t)BO_ * 2 * BETA_,      // [32][10][1024] 1/na|1/nb
  WS_CAT   = WS_RN    + (size_t)BO_ * 10 * E_,        // [32][4096]
  WS_END   = WS_CAT   + (size_t)BO_ * 8 * BETA_,
};

__device__ __forceinline__ float relu_(float v) { return v > 0.f ? v : 0.f; }

// ---------------- K1: per-chunk segment partial sums (2-deep unrolled loads) ----------
__global__ void k1_segsum(const float* __restrict__ hidden, const int* __restrict__ idx,
                          float* __restrict__ Spart) {
    const int chunk = blockIdx.x;  // 0..15, 64 rows each
    const int bo = blockIdx.y;
    const int b = bo >> 2;
    int cuts[13];
    cuts[0] = 1;
#pragma unroll
    for (int i = 0; i < 12; ++i) cuts[i + 1] = idx[b * NSEG_ + i];
    const int e4 = threadIdx.x << 2;
    float* sp = Spart + ((size_t)(bo * NCH_ + chunk) * 12) * E_ + e4;
    const float4 z = make_float4(0.f, 0.f, 0.f, 0.f);
#pragma unroll
    for (int m = 0; m < 12; ++m) *reinterpret_cast<float4*>(sp + (size_t)m * E_) = z;
    const int l0 = chunk * 64;
    const int l1 = l0 + 64;
    int lo = l0 < 1 ? 1 : l0;
    const int hi = l1 < cuts[12] ? l1 : cuts[12];
    if (lo >= hi) return;
    const float* base = hidden + (size_t)bo * (L_ * E_) + e4;
    int j = 0;
    while (j < 11 && cuts[j + 1] <= lo) ++j;
    int l = lo;
    while (l < hi) {
        const int e2 = (j < 11 && cuts[j + 1] < hi) ? cuts[j + 1] : hi;
        float sx = 0.f, sy = 0.f, sz = 0.f, sw = 0.f;
        float tx = 0.f, ty = 0.f, tz = 0.f, tw = 0.f;
        for (; l + 1 < e2; l += 2) {  // two independent loads in flight
            const float4 v0 = *reinterpret_cast<const float4*>(base + (size_t)l * E_);
            const float4 v1 = *reinterpret_cast<const float4*>(base + (size_t)(l + 1) * E_);
            sx += v0.x; sy += v0.y; sz += v0.z; sw += v0.w;
            tx += v1.x; ty += v1.y; tz += v1.z; tw += v1.w;
        }
        if (l < e2) {
            const float4 v = *reinterpret_cast<const float4*>(base + (size_t)l * E_);
            sx += v.x; sy += v.y; sz += v.z; sw += v.w;
            ++l;
        }
        float4 s; s.x = sx + tx; s.y = sy + ty; s.z = sz + tz; s.w = sw + tw;
        *reinterpret_cast<float4*>(sp + (size_t)j * E_) = s;  // block-owned slice
        ++j;
    }
}

// ---------------- K2: reduce chunk partials -> segment means X[32][13][1024] ----------
__global__ __launch_bounds__(256) void k2_means(
    const float* __restrict__ Spart, const int* __restrict__ idx,
    float* __restrict__ X) {
    const int bo = blockIdx.y;
    const int col = blockIdx.x * 256 + threadIdx.x;
    const int b = bo >> 2;
    int cuts[13];
    cuts[0] = 1;
#pragma unroll
    for (int i = 0; i < 12; ++i) cuts[i + 1] = idx[b * NSEG_ + i];
    const float* sp = Spart + (size_t)bo * NCH_ * 12 * E_ + col;
    float allc = 0.f;
#pragma unroll
    for (int m = 0; m < 12; ++m) {
        float s = 0.f;
#pragma unroll
        for (int ch = 0; ch < NCH_; ++ch) s += sp[((size_t)ch * 12 + m) * E_];
        X[((size_t)bo * 13 + m) * E_ + col] = s / (float)(cuts[m + 1] - cuts[m]);
        if (m < 10) allc += s;
    }
    X[((size_t)bo * 13 + 12) * E_ + col] = allc / (float)(cuts[10] - 1);
}

// ---------------- split-K GEMM, partial-slice output (no atomics) ---------------------
// XF 0: identity | 1: 1+relu(sum_p+xb), side TE | 2: relu(sum_p+xb) | 5: pool2 -> RN
template<int M, int ML, int K, int N, int KC, int BOG, int XF, int NPART>
__global__ __launch_bounds__(256) void gemm_sk(
    const float* __restrict__ Xb, const float* __restrict__ xbias,
    const float* __restrict__ W, float* __restrict__ OUT,
    const float* __restrict__ A0, const float* __restrict__ A1,
    const float* __restrict__ A2, const float* __restrict__ A3,
    float* __restrict__ SIDE, float* __restrict__ SIDE2) {
    const int kidx = blockIdx.x;
    const int k0 = kidx * KC;
    const int bo0 = blockIdx.y * BOG;
    const int c = blockIdx.z * 256 + threadIdx.x;
    const int tid = threadIdx.x;
    __shared__ __align__(16) float xs[BOG * ML * KC];

    for (int i = tid; i < BOG * ML * KC; i += 256) {
        const int kk = i % KC;
        const int rm = i / KC;
        const int m = rm % ML;
        const int bb = rm / ML;
        const int bo = bo0 + bb;
        const int k = k0 + kk;
        float v;
        if constexpr (XF == 0) {
            v = Xb[((size_t)bo * ML + m) * K + k];
        } else if constexpr (XF == 1) {
            float s = xbias[k];
#pragma unroll
            for (int p = 0; p < NPART; ++p)
                s += Xb[(((size_t)p * BO_ + bo) * ML + m) * K + k];
            v = 1.f + relu_(s);
            SIDE[((size_t)bo * ML + m) * K + k] = v;  // TE
        } else if constexpr (XF == 2) {
            float s = xbias[k];
#pragma unroll
            for (int p = 0; p < NPART; ++p)
                s += Xb[(((size_t)p * BO_ + bo) * ML + m) * K + k];
            v = relu_(s);
        } else {  // XF == 5: pool-2 2-way softmax -> RN
            const int col = k & 511, half = k >> 9;
            const float tj = A0[((size_t)bo * 10 + m) * BETA_ + col];  // T1B (has +ba)
            float tI = A2[col];
#pragma unroll
            for (int p = 0; p < NPART; ++p)
                tI += A1[((size_t)p * BO_ + bo) * BETA_ + col];
            const float mx = fmaxf(tj, tI);
            const float e0 = expf(tj - mx);
            const float e1 = expf(tI - mx);
            const float ea = A3[((size_t)bo * 13 + m) * E_ + half * BETA_ + col];  // TE
            const float iv = SIDE2[(size_t)bo * 1024 + k];                         // IAB
            v = (e0 + e1) / (e0 * ea + e1 * iv);
            SIDE[((size_t)bo * 10 + m) * E_ + k] = v;  // RN
        }
        xs[i] = v;
    }
    __syncthreads();

    float acc[BOG][M];
#pragma unroll
    for (int b = 0; b < BOG; ++b)
#pragma unroll
        for (int m = 0; m < M; ++m) acc[b][m] = 0.f;
    const float* __restrict__ wp = W + (size_t)k0 * N + c;
    for (int k4 = 0; k4 < KC / 4; ++k4) {
        const float w0 = wp[(size_t)(4 * k4 + 0) * N];
        const float w1 = wp[(size_t)(4 * k4 + 1) * N];
        const float w2 = wp[(size_t)(4 * k4 + 2) * N];
        const float w3 = wp[(size_t)(4 * k4 + 3) * N];
#pragma unroll
        for (int b = 0; b < BOG; ++b) {
#pragma unroll
            for (int m = 0; m < M; ++m) {
                const float4 xv = *reinterpret_cast<const float4*>(&xs[(b * ML + m) * KC + 4 * k4]);
                float a = acc[b][m];
                a = fmaf(xv.x, w0, a);
                a = fmaf(xv.y, w1, a);
                a = fmaf(xv.z, w2, a);
                a = fmaf(xv.w, w3, a);
                acc[b][m] = a;
            }
        }
    }
#pragma unroll
    for (int b = 0; b < BOG; ++b) {
        float* op = OUT + (((size_t)kidx * BO_ + bo0 + b) * M) * N + c;
#pragma unroll
        for (int m = 0; m < M; ++m) op[(size_t)m * N] = acc[b][m];  // plain store
    }
}

// ---------------- t_iab: pool-1 logits + softmax -> T1B, IAB (128 blocks x 128 thr) ---
__global__ void __launch_bounds__(128) t_iab(
    const float* __restrict__ T1P, const float* __restrict__ ba,
    const float* __restrict__ TE, float* __restrict__ T1B,
    float* __restrict__ IAB) {
    const int bo = blockIdx.x;
    const int c = blockIdx.y * 128 + threadIdx.x;  // 0..511
    const float bac = ba[c];
    float t[10], mx = -1e30f;
#pragma unroll
    for (int j = 0; j < 10; ++j) {
        float s = bac;
#pragma unroll
        for (int p = 0; p < 8; ++p)
            s += T1P[(((size_t)p * BO_ + bo) * 10 + j) * BETA_ + c];
        t[j] = s;
        T1B[((size_t)bo * 10 + j) * BETA_ + c] = s;
        mx = fmaxf(mx, s);
    }
    float p[10], sw = 0.f;
#pragma unroll
    for (int j = 0; j < 10; ++j) { p[j] = expf(t[j] - mx); sw += p[j]; }
    float ia = 0.f, ib = 0.f;
#pragma unroll
    for (int j = 0; j < 10; ++j) {
        ia = fmaf(p[j], TE[((size_t)bo * 13 + j) * E_ + c], ia);
        ib = fmaf(p[j], TE[((size_t)bo * 13 + j) * E_ + BETA_ + c], ib);
    }
    IAB[(size_t)bo * 1024 + c] = ia / sw;
    IAB[(size_t)bo * 1024 + BETA_ + c] = ib / sw;
}

// ---------------- t_cat: pool-3 softmax + full cat build (512 blocks) -----------------
__global__ __launch_bounds__(256) void t_cat(
    const float* __restrict__ T3P, const float* __restrict__ ba,
    const float* __restrict__ RN, const float* __restrict__ TE,
    float* __restrict__ CAT) {
    const int bo = blockIdx.y;
    const int k = blockIdx.x * 256 + threadIdx.x;  // 0..4095
    float v;
    if (k < 1024) {
        const int col = k & 511;
        const float bac = ba[col];
        float t[10], mx = -1e30f;
#pragma unroll
        for (int j = 0; j < 10; ++j) {
            float s = bac;
#pragma unroll
            for (int p = 0; p < 8; ++p)
                s += T3P[(((size_t)p * BO_ + bo) * 10 + j) * BETA_ + col];
            t[j] = s;
            mx = fmaxf(mx, s);
        }
        float sw = 0.f, acc = 0.f;
#pragma unroll
        for (int j = 0; j < 10; ++j) {
            const float pj = expf(t[j] - mx);
            sw += pj;
            acc = fmaf(pj, RN[((size_t)bo * 10 + j) * E_ + k], acc);
        }
        v = sw / acc;
    } else {
        const int region = k >> 10;  // 1,2,3
        const int row = (region == 1) ? 12 : (region == 2) ? 11 : 10;
        v = TE[((size_t)bo * 13 + row) * E_ + (k & 1023)];
    }
    CAT[(size_t)bo * 4096 + k] = v;
}

// ---------------- final: out[bo] = relu(sum_p HFpart + bl0) . Wl + bl -----------------
__global__ void __launch_bounds__(512) k_final(
    const float* __restrict__ HFP, const float* __restrict__ bl0,
    const float* __restrict__ Wl, const float* __restrict__ bl,
    float* __restrict__ out) {
    const int bo = blockIdx.x;
    const int c = threadIdx.x;
    float s = bl0[c];
#pragma unroll
    for (int p = 0; p < 32; ++p) s += HFP[((size_t)p * BO_ + bo) * BETA_ + c];
    float partial = relu_(s) * Wl[c];
#pragma unroll
    for (int off = 32; off > 0; off >>= 1) partial += __shfl_down(partial, off, 64);
    __shared__ float red[8];
    if ((c & 63) == 0) red[c >> 6] = partial;
    __syncthreads();
    if (c == 0) out[bo] = red[0] + red[1] + red[2] + red[3] + red[4] + red[5] + red[6] + red[7] + bl[0];
}

extern "C" void kernel_launch(void* const* d_in, const int* in_sizes, int n_in,
                              void* d_out, int out_size, void* d_ws, size_t ws_size,
                              hipStream_t stream) {
    const float* hidden = (const float*)d_in[0];
    const int* idx = (const int*)d_in[1];
    const float* Wp  = (const float*)d_in[2];
    const float* bp  = (const float*)d_in[3];
    const float* Wa0 = (const float*)d_in[4];
    const float* ba0 = (const float*)d_in[5];
    const float* Wa  = (const float*)d_in[6];
    const float* ba  = (const float*)d_in[7];
    const float* Wl0 = (const float*)d_in[8];
    const float* bl0 = (const float*)d_in[9];
    const float* Wl  = (const float*)d_in[10];
    const float* bl  = (const float*)d_in[11];
    float* ws = (float*)d_ws;
    float* SPART = ws + WS_SPART;
    float* X     = ws + WS_X;
    float* P1P   = ws + WS_P1P;
    float* H1P   = ws + WS_H1P;
    float* T1P   = ws + WS_T1P;
    float* H2P   = ws + WS_H2P;
    float* T2P   = ws + WS_T2P;
    float* H3P   = ws + WS_H3P;
    float* T3P   = ws + WS_T3P;
    float* HFP   = ws + WS_HFP;
    float* TE    = ws + WS_TE;
    float* T1B   = ws + WS_T1B;
    float* IAB   = ws + WS_IAB;
    float* RN    = ws + WS_RN;
    float* CAT   = ws + WS_CAT;
    const float* NUL = nullptr;

    k1_segsum<<<dim3(NCH_, BO_), 256, 0, stream>>>(hidden, idx, SPART);
    k2_means<<<dim3(4, BO_), 256, 0, stream>>>(SPART, idx, X);
    // G1: P1P[8] = X @ Wp  (M=13,K=1024,N=1024, ksplit=8, BOG=2) -> 512 blocks [R5 exact]
    gemm_sk<13, 13, 1024, 1024, 128, 2, 0, 1>
        <<<dim3(8, 16, 4), 256, 0, stream>>>(X, NUL, Wp, P1P, NUL, NUL, NUL, NUL, nullptr, nullptr);
    // G2: H1P[16] = TE(rows<10) @ Wa0 ; side TE (sums 8 P1 partials) -> 512 blocks [R5 exact]
    gemm_sk<10, 13, 1024, 512, 64, 2, 1, 8>
        <<<dim3(16, 16, 2), 256, 0, stream>>>(P1P, bp, Wa0, H1P, NUL, NUL, NUL, NUL, TE, nullptr);
    // G3: T1P[8] = relu(sum H1P + ba0) @ Wa -> 256 blocks [R5 exact]
    gemm_sk<10, 10, 512, 512, 64, 2, 2, 16>
        <<<dim3(8, 16, 2), 256, 0, stream>>>(H1P, ba0, Wa, T1P, NUL, NUL, NUL, NUL, nullptr, nullptr);
    // pool-1 softmax: wide (128 blocks x 128 thr)
    t_iab<<<dim3(BO_, 4), 128, 0, stream>>>(T1P, ba, TE, T1B, IAB);
    // G4: H2P[8] = IAB @ Wa0  (identity loader, staging 4 loads/thr) -> 64 blocks
    gemm_sk<1, 1, 1024, 512, 128, 8, 0, 1>
        <<<dim3(8, 4, 2), 256, 0, stream>>>(IAB, NUL, Wa0, H2P, NUL, NUL, NUL, NUL, nullptr, nullptr);
    // G5: T2P[8] = relu(sum H2P + ba0) @ Wa -> 64 blocks [R5 exact]
    gemm_sk<1, 1, 512, 512, 64, 8, 2, 8>
        <<<dim3(8, 4, 2), 256, 0, stream>>>(H2P, ba0, Wa, T2P, NUL, NUL, NUL, NUL, nullptr, nullptr);
    // G6: H3P[16] = RN @ Wa0 ; pool-2 2-way softmax loader; side RN -> 512 blocks [R5 exact]
    gemm_sk<10, 10, 1024, 512, 64, 2, 5, 8>
        <<<dim3(16, 16, 2), 256, 0, stream>>>(NUL, NUL, Wa0, H3P, T1B, T2P, ba, TE, RN, IAB);
    // G7: T3P[8] = relu(sum H3P + ba0) @ Wa -> 256 blocks [R5 exact]
    gemm_sk<10, 10, 512, 512, 64, 2, 2, 16>
        <<<dim3(8, 16, 2), 256, 0, stream>>>(H3P, ba0, Wa, T3P, NUL, NUL, NUL, NUL, nullptr, nullptr);
    // pool-3 softmax + cat build: wide (512 blocks)
    t_cat<<<dim3(16, BO_), 256, 0, stream>>>(T3P, ba, RN, TE, CAT);
    // G8: HFP[32] = CAT @ Wl0  (identity loader, K=4096) -> 256 blocks
    gemm_sk<1, 1, 4096, 512, 128, 8, 0, 1>
        <<<dim3(32, 4, 2), 256, 0, stream>>>(CAT, NUL, Wl0, HFP, NUL, NUL, NUL, NUL, nullptr, nullptr);
    k_final<<<BO_, 512, 0, stream>>>(HFP, bl0, Wl, bl, (float*)d_out);
}